// Round 1
// baseline (279.015 us; speedup 1.0000x reference)
//
#include <hip/hip_runtime.h>

#define DEVFN __device__ __forceinline__

typedef unsigned short u16;
typedef __attribute__((ext_vector_type(8))) unsigned short u16x8;
typedef __attribute__((ext_vector_type(4))) unsigned short u16x4;
typedef __attribute__((ext_vector_type(8))) __bf16 bf16x8;
typedef __attribute__((ext_vector_type(4))) float f32x4;

// ---------- helpers ----------
DEVFN u16 f2bf_hw(float f) {  // hardware RNE convert (single v_cvt)
    return __builtin_bit_cast(u16, (__bf16)f);
}

DEVFN float bf2f(u16 h) {
    unsigned u = (unsigned)h << 16;
    return __builtin_bit_cast(float, u);
}

DEVFN bf16x8 ldfrag(const u16* p) {
    return __builtin_bit_cast(bf16x8, *(const u16x8*)p);
}

DEVFN f32x4 mfma16(bf16x8 a, bf16x8 b, f32x4 c) {
    return __builtin_amdgcn_mfma_f32_16x16x32_bf16(a, b, c, 0, 0, 0);
}

// async global->LDS, 16B per lane; l must be the wave-uniform base
DEVFN void async16(const u16* g, u16* l) {
    __builtin_amdgcn_global_load_lds(
        (const __attribute__((address_space(1))) void*)g,
        (__attribute__((address_space(3))) void*)l, 16, 0, 0);
}

// ---------- fp32->bf16 converts + mask compaction, ONE dispatch ----------
__global__ __launch_bounds__(256) void conv_all(const float* __restrict__ y,
                                                const float* __restrict__ w0,
                                                const float* __restrict__ w1,
                                                const float* __restrict__ w2,
                                                const float* __restrict__ w3,
                                                u16* __restrict__ yb,
                                                u16* __restrict__ wb,
                                                const int* __restrict__ mask,
                                                int* __restrict__ idx,
                                                int* __restrict__ cnt) {
    const int b = blockIdx.x;
    if (b >= 12288) {
        const int wave = threadIdx.x >> 6, lane = threadIdx.x & 63;
        for (int bb = wave; bb < 8; bb += 4) {
            const int* m = mask + bb * 1024;
            int* ib = idx + bb * 1024;
            int base = 0;
            for (int t = 0; t < 16; ++t) {
                const int pos = t * 64 + lane;
                const int valid = (m[pos] == 0) ? 1 : 0;
                const unsigned long long bal = __ballot(valid);
                const int pre = __popcll(bal & ((1ull << lane) - 1ull));
                if (valid) ib[base + pre] = pos;
                base += (int)__popcll(bal);
            }
            if (lane == 0) cnt[bb] = base;
            for (int i = base + lane; i < 1024; i += 64) ib[i] = 0;  // safe pad
        }
        return;
    }
    const float* src;
    u16* dst;
    int i;
    if (b < 8192) {
        src = y; dst = yb;
        i = b * 1024 + threadIdx.x * 4;
    } else {
        const int g = (b - 8192) >> 10;
        src = g == 0 ? w0 : (g == 1 ? w1 : (g == 2 ? w2 : w3));
        dst = wb + (size_t)g * 1024 * 1024;
        i = ((b - 8192) & 1023) * 1024 + threadIdx.x * 4;
    }
    const float4 v = *(const float4*)&src[i];
    u16x4 o;
    o.x = f2bf_hw(v.x); o.y = f2bf_hw(v.y);
    o.z = f2bf_hw(v.z); o.w = f2bf_hw(v.w);
    *(u16x4*)&dst[i] = o;
}

// ---------- 8-phase 256x256 GEMM (T1+T2+T3+T4+T5), bf16 out ----------
// C[M,N] = A[M,K] * Bt[N,K]^T + bias. 512 thr = 8 waves (2M x 4N), per-wave
// 128x64 output, BK=64, LDS 128 KiB = 2 buf x {A,B} x 2 halves x [128][64].
//
// Per K-tile, 4 phases (16 MFMA each). Register scheme: ALL 8 B-frags live
//   p1: read A mi0-3 (8 ds) + B ni0-1 (4 ds)  -> mfma m0-3 x n0-1
//   p2: read B ni2-3 (4 ds)                   -> mfma m0-3 x n2-3
//   p3: read A mi4-7 (8 ds)                   -> mfma m4-7 x n0-1
//   p4: (no reads)                            -> mfma m4-7 x n2-3
// => B-half of tile t fully read after p2's 2nd barrier; A-half after p3's.
// Stage ledger (1-2 half-tiles/phase, global_load_lds, WAR-safe by the above):
//   t.p1: stage (t+1).A1   [buf^1, old data = (t-1).A1, read done at (t-1).p3]
//   t.p3: stage (t+2).B0   [buf,  old = t.B0, read done at t.p2]
//   t.p4: stage (t+2).A0 + (t+2).B1  [old reads done at t.p3 / t.p2]
// Checkpoint at t.p4 (before 2nd barrier): vmcnt(6) = newest 3 half-tiles
// ((t+2).B0/A0/B1) may be in flight; (t+1).A1 and older guaranteed done ->
// tile t+1 fully staged before its p1 reads. Tail: t>=NT-2 drains vmcnt(0).
// Swizzle (rule 21, both sides): linear LDS dest; source fetches slot
// sc^sr of its row; reads XOR slot with row&7 -> 16 lanes hit all 8 16B
// slots (2-way aliasing = free). K-chunk order identical to old kernel
// (k ascending in 32-chunks) -> bitwise-identical accumulation.
__global__ __launch_bounds__(512, 2) void gemm8_bt(const u16* __restrict__ A,
                                                   const u16* __restrict__ Bt,
                                                   const float* __restrict__ b0,
                                                   const float* __restrict__ b1,
                                                   const float* __restrict__ b2,
                                                   u16* __restrict__ C0,
                                                   u16* __restrict__ C1,
                                                   u16* __restrict__ C2,
                                                   int K, int NBX) {
    __shared__ u16 lds[2][2][2][8192];  // [buf][A=0/B=1][half][128r x 64c]
    const int NT = K >> 6;
    const int tid = threadIdx.x;
    const int wave = tid >> 6, lane = tid & 63;
    const int quad = lane >> 4, l16 = lane & 15;
    const int wm = wave >> 2;  // 0..1: A-half / m 128-block
    const int wn = wave & 3;   // 0..3: n 64-block; B-half = wn>>1
    // XCD-bijective chunked swizzle (grid % 8 == 0 by construction: 384)
    const int nwg = gridDim.x;
    const int cpx = nwg >> 3;
    const int sb = (blockIdx.x & 7) * cpx + (blockIdx.x >> 3);
    const int bx = sb % NBX, by = sb / NBX;
    const int m0 = by * 256, n0 = bx * 256;
    // staging: per-thread pre-swizzled source, linear LDS dest
    const int sr = lane >> 3, sc = lane & 7;
    const int scs = ((sc ^ sr) << 3);
    const u16* Ag = A + (size_t)(m0 + wave * 8 + sr) * K + scs;
    const u16* Bg = Bt + (size_t)(n0 + wave * 8 + sr) * K + scs;
    const size_t hstep = (size_t)128 * K;  // half-tile row step
    // read-side swizzled offsets (u16 units); ks=1 frag = rof ^ 32
    const int rof = l16 * 64 + ((quad ^ (l16 & 7)) << 3);
    const int nioff = (wn & 1) * 4096;

#define STAGE(gptr, lptr)                                  \
    do {                                                   \
        async16((gptr), (lptr) + wave * 512);              \
        async16((gptr) + (size_t)64 * K,                   \
                (lptr) + 4096 + wave * 512);               \
    } while (0)

    f32x4 acc[8][4] = {};

    // prologue: t0.{B0,A0,B1,A1}, t1.{B0,A0,B1} = 7 half-tiles (14 loads)
    STAGE(Bg, &lds[0][1][0][0]);
    STAGE(Ag, &lds[0][0][0][0]);
    STAGE(Bg + hstep, &lds[0][1][1][0]);
    STAGE(Ag + hstep, &lds[0][0][1][0]);
    STAGE(Bg + 64, &lds[1][1][0][0]);
    STAGE(Ag + 64, &lds[1][0][0][0]);
    STAGE(Bg + hstep + 64, &lds[1][1][1][0]);
    asm volatile("s_waitcnt vmcnt(6)" ::: "memory");  // t0 complete
    __builtin_amdgcn_s_barrier();

    for (int t = 0; t < NT; ++t) {
        const int buf = t & 1;
        const u16* Ar = &lds[buf][0][wm][0];
        const u16* Br = &lds[buf][1][wn >> 1][0] + nioff;
        bf16x8 af[4][2], bfr[4][2];
        // ---- phase 1: A mi0-3 + B ni0-1 ----
        #pragma unroll
        for (int mi = 0; mi < 4; ++mi) {
            af[mi][0] = ldfrag(Ar + mi * 1024 + rof);
            af[mi][1] = ldfrag(Ar + mi * 1024 + (rof ^ 32));
        }
        #pragma unroll
        for (int ni = 0; ni < 2; ++ni) {
            bfr[ni][0] = ldfrag(Br + ni * 1024 + rof);
            bfr[ni][1] = ldfrag(Br + ni * 1024 + (rof ^ 32));
        }
        if (t + 1 < NT)
            STAGE(Ag + hstep + (size_t)(t + 1) * 64, &lds[buf ^ 1][0][1][0]);
        __builtin_amdgcn_s_barrier();
        asm volatile("s_waitcnt lgkmcnt(0)" ::: "memory");
        __builtin_amdgcn_s_setprio(1);
        #pragma unroll
        for (int mi = 0; mi < 4; ++mi)
            #pragma unroll
            for (int ni = 0; ni < 2; ++ni) {
                acc[mi][ni] = mfma16(af[mi][0], bfr[ni][0], acc[mi][ni]);
                acc[mi][ni] = mfma16(af[mi][1], bfr[ni][1], acc[mi][ni]);
            }
        __builtin_amdgcn_s_setprio(0);
        __builtin_amdgcn_s_barrier();
        // ---- phase 2: B ni2-3 ----
        #pragma unroll
        for (int ni = 2; ni < 4; ++ni) {
            bfr[ni][0] = ldfrag(Br + ni * 1024 + rof);
            bfr[ni][1] = ldfrag(Br + ni * 1024 + (rof ^ 32));
        }
        __builtin_amdgcn_s_barrier();
        asm volatile("s_waitcnt lgkmcnt(0)" ::: "memory");
        __builtin_amdgcn_s_setprio(1);
        #pragma unroll
        for (int mi = 0; mi < 4; ++mi)
            #pragma unroll
            for (int ni = 2; ni < 4; ++ni) {
                acc[mi][ni] = mfma16(af[mi][0], bfr[ni][0], acc[mi][ni]);
                acc[mi][ni] = mfma16(af[mi][1], bfr[ni][1], acc[mi][ni]);
            }
        __builtin_amdgcn_s_setprio(0);
        __builtin_amdgcn_s_barrier();
        // ---- phase 3: A mi4-7 ----
        #pragma unroll
        for (int mi = 0; mi < 4; ++mi) {
            af[mi][0] = ldfrag(Ar + (mi + 4) * 1024 + rof);
            af[mi][1] = ldfrag(Ar + (mi + 4) * 1024 + (rof ^ 32));
        }
        if (t + 2 < NT)
            STAGE(Bg + (size_t)(t + 2) * 64, &lds[buf][1][0][0]);
        __builtin_amdgcn_s_barrier();
        asm volatile("s_waitcnt lgkmcnt(0)" ::: "memory");
        __builtin_amdgcn_s_setprio(1);
        #pragma unroll
        for (int mi = 0; mi < 4; ++mi)
            #pragma unroll
            for (int ni = 0; ni < 2; ++ni) {
                acc[mi + 4][ni] = mfma16(af[mi][0], bfr[ni][0], acc[mi + 4][ni]);
                acc[mi + 4][ni] = mfma16(af[mi][1], bfr[ni][1], acc[mi + 4][ni]);
            }
        __builtin_amdgcn_s_setprio(0);
        __builtin_amdgcn_s_barrier();
        // ---- phase 4: no reads ----
        if (t + 2 < NT) {
            STAGE(Ag + (size_t)(t + 2) * 64, &lds[buf][0][0][0]);
            STAGE(Bg + hstep + (size_t)(t + 2) * 64, &lds[buf][1][1][0]);
        }
        __builtin_amdgcn_s_setprio(1);
        #pragma unroll
        for (int mi = 0; mi < 4; ++mi)
            #pragma unroll
            for (int ni = 2; ni < 4; ++ni) {
                acc[mi + 4][ni] = mfma16(af[mi][0], bfr[ni][0], acc[mi + 4][ni]);
                acc[mi + 4][ni] = mfma16(af[mi][1], bfr[ni][1], acc[mi + 4][ni]);
            }
        __builtin_amdgcn_s_setprio(0);
        if (t < NT - 2)
            asm volatile("s_waitcnt vmcnt(6)" ::: "memory");
        else
            asm volatile("s_waitcnt vmcnt(0)" ::: "memory");
        __builtin_amdgcn_s_barrier();
    }
#undef STAGE
    // epilogue: bias + bf16 store, col>>10 selects q/k/v buffer
    const int wmrow = m0 + wm * 128 + quad * 4;
    #pragma unroll
    for (int ni = 0; ni < 4; ++ni) {
        const int col = n0 + wn * 64 + ni * 16 + l16;
        const int cs = col >> 10;
        const int c = col & 1023;
        const float* bp = cs == 0 ? b0 : (cs == 1 ? b1 : b2);
        u16* cp = cs == 0 ? C0 : (cs == 1 ? C1 : C2);
        const float bb = bp[c];
        #pragma unroll
        for (int mi = 0; mi < 8; ++mi)
            #pragma unroll
            for (int r = 0; r < 4; ++r) {
                const int row = wmrow + mi * 16 + r;
                cp[(size_t)row * 1024 + c] = f2bf_hw(acc[mi][ni][r] + bb);
            }
    }
}

// ---------- legacy 128^2 GEMM (kept for M-proj: N=1024 -> 512 blocks) ----------
__global__ __launch_bounds__(256, 4) void gemm_bt(const u16* __restrict__ A,
                                                  const u16* __restrict__ Bt,
                                                  const float* __restrict__ b0,
                                                  const float* __restrict__ b1,
                                                  const float* __restrict__ b2,
                                                  u16* __restrict__ C0,
                                                  u16* __restrict__ C1,
                                                  u16* __restrict__ C2,
                                                  int K) {
    __shared__ u16 lA[128 * 32];
    __shared__ u16 lB[128 * 32];
    const int tid = threadIdx.x;
    const int wave = tid >> 6, lane = tid & 63;
    const int quad = lane >> 4, l16 = lane & 15;
    const int n0 = blockIdx.x * 128, m0 = blockIdx.y * 128;
    const int wm = (wave >> 1) * 64, wn = (wave & 1) * 64;
    const int srow = tid >> 2, scol = (tid & 3) * 8;
    const u16* Ag0 = A + (size_t)(m0 + srow) * K + scol;
    const u16* Ag1 = A + (size_t)(m0 + 64 + srow) * K + scol;
    const u16* Bg0 = Bt + (size_t)(n0 + srow) * K + scol;
    const u16* Bg1 = Bt + (size_t)(n0 + 64 + srow) * K + scol;
    u16* lA0 = &lA[wave * 512];
    u16* lA1 = &lA[2048 + wave * 512];
    u16* lB0 = &lB[wave * 512];
    u16* lB1 = &lB[2048 + wave * 512];
    f32x4 acc[4][4] = {};
    for (int k0 = 0; k0 < K; k0 += 32) {
        __syncthreads();
        async16(Ag0 + k0, lA0);
        async16(Ag1 + k0, lA1);
        async16(Bg0 + k0, lB0);
        async16(Bg1 + k0, lB1);
        __syncthreads();
        bf16x8 af[4], bfr[4];
        #pragma unroll
        for (int i = 0; i < 4; ++i)
            af[i] = ldfrag(&lA[(wm + i * 16 + l16) * 32 + quad * 8]);
        #pragma unroll
        for (int i = 0; i < 4; ++i)
            bfr[i] = ldfrag(&lB[(wn + i * 16 + l16) * 32 + quad * 8]);
        #pragma unroll
        for (int mi = 0; mi < 4; ++mi)
            #pragma unroll
            for (int ni = 0; ni < 4; ++ni)
                acc[mi][ni] = mfma16(af[mi], bfr[ni], acc[mi][ni]);
    }
    #pragma unroll
    for (int mi = 0; mi < 4; ++mi) {
        #pragma unroll
        for (int ni = 0; ni < 4; ++ni) {
            const int col = n0 + wn + ni * 16 + l16;
            const int cs = col >> 10;
            const int c = col & 1023;
            const float* bp = cs == 0 ? b0 : (cs == 1 ? b1 : b2);
            u16* cp = cs == 0 ? C0 : (cs == 1 ? C1 : C2);
            const float bb = bp[c];
            #pragma unroll
            for (int r = 0; r < 4; ++r) {
                const int row = m0 + wm + mi * 16 + quad * 4 + r;
                cp[(size_t)row * 1024 + c] = f2bf_hw(acc[mi][ni][r] + bb);
            }
        }
    }
}

// ---------- flash attention over COMPACTED K/V, in-kernel V transpose ----------
__global__ __launch_bounds__(256) void attn(const u16* __restrict__ qb,
                                            const u16* __restrict__ kb,
                                            const u16* __restrict__ vb,
                                            const int* __restrict__ idxb,
                                            const int* __restrict__ cntb,
                                            u16* __restrict__ attb) {
    const int lin = blockIdx.x;
    const int xcd = lin & 7, slot = lin >> 3;          // slot 0..127
    const int bh = xcd * 16 + (slot >> 3);
    const int q0 = (slot & 7) * 128;
    const int bb = bh >> 4, h = bh & 15;
    const int tid = threadIdx.x, wave = tid >> 6, lane = tid & 63;
    const int quad = lane >> 4, l16 = lane & 15;
    __shared__ u16 lK[64 * 72];
    __shared__ u16 lV[64 * 72];
    __shared__ u16 lP[128 * 72];

    const int cn = cntb[bb];
    const int kEnd = (cn + 63) & ~63;
    const int* ib = idxb + bb * 1024;

    bf16x8 aq[2][2];
    #pragma unroll
    for (int rg = 0; rg < 2; ++rg) {
        const int qrow = q0 + wave * 32 + rg * 16 + l16;
        const u16* qp = qb + (size_t)(bb * 1024 + qrow) * 1024 + h * 64 + quad * 8;
        aq[rg][0] = ldfrag(qp);
        aq[rg][1] = ldfrag(qp + 32);
    }

    f32x4 o[2][4] = {};
    float ps_acc[2][4] = {};

    const int srow = tid >> 3, scol = (tid & 7) * 8;
    const u16* kbase = kb + (size_t)(bb * 1024) * 1024 + h * 64 + scol;
    const u16* vbase = vb + (size_t)(bb * 1024) * 1024 + h * 64 + scol;

    int gi0 = ib[srow], gi1 = ib[srow + 32];
    u16x8 nk0 = *(const u16x8*)(kbase + (size_t)gi0 * 1024);
    u16x8 nk1 = *(const u16x8*)(kbase + (size_t)gi1 * 1024);
    u16x8 nv0 = *(const u16x8*)(vbase + (size_t)gi0 * 1024);
    u16x8 nv1 = *(const u16x8*)(vbase + (size_t)gi1 * 1024);

    const float C = 0.18033688011112043f;  // 0.125 * log2(e)

    for (int kt = 0; kt < kEnd; kt += 64) {
        __syncthreads();
        *(u16x8*)&lK[srow * 72 + scol] = nk0;
        *(u16x8*)&lK[(srow + 32) * 72 + scol] = nk1;
        #pragma unroll
        for (int j = 0; j < 8; ++j) {
            lV[(scol + j) * 72 + srow] = nv0[j];
            lV[(scol + j) * 72 + srow + 32] = nv1[j];
        }
        __syncthreads();
        const int ktn = kt + 64;
        if (ktn < kEnd) {
            gi0 = ib[ktn + srow]; gi1 = ib[ktn + srow + 32];
            nk0 = *(const u16x8*)(kbase + (size_t)gi0 * 1024);
            nk1 = *(const u16x8*)(kbase + (size_t)gi1 * 1024);
            nv0 = *(const u16x8*)(vbase + (size_t)gi0 * 1024);
            nv1 = *(const u16x8*)(vbase + (size_t)gi1 * 1024);
        }

        bf16x8 kf[4][2];
        #pragma unroll
        for (int n = 0; n < 4; ++n) {
            kf[n][0] = ldfrag(&lK[(n * 16 + l16) * 72 + quad * 8]);
            kf[n][1] = ldfrag(&lK[(n * 16 + l16) * 72 + 32 + quad * 8]);
        }
        f32x4 s[2][4];
        #pragma unroll
        for (int rg = 0; rg < 2; ++rg)
            #pragma unroll
            for (int n = 0; n < 4; ++n) {
                f32x4 t = {};
                t = mfma16(aq[rg][0], kf[n][0], t);
                t = mfma16(aq[rg][1], kf[n][1], t);
                s[rg][n] = t;
            }
        float bias[4];
        #pragma unroll
        for (int n = 0; n < 4; ++n)
            bias[n] = (kt + n * 16 + l16 < cn) ? 0.0f : -1e9f;
        #pragma unroll
        for (int rg = 0; rg < 2; ++rg)
            #pragma unroll
            for (int n = 0; n < 4; ++n)
                #pragma unroll
                for (int r = 0; r < 4; ++r) {
                    const float p =
                        __builtin_amdgcn_exp2f(__builtin_fmaf(s[rg][n][r], C, bias[n]));
                    ps_acc[rg][r] += p;
                    lP[(wave * 32 + rg * 16 + quad * 4 + r) * 72 + n * 16 + l16] =
                        f2bf_hw(p);
                }
        __asm__ __volatile__("s_waitcnt lgkmcnt(0)" ::: "memory");
        bf16x8 ap[2][2];
        #pragma unroll
        for (int rg = 0; rg < 2; ++rg) {
            ap[rg][0] = ldfrag(&lP[(wave * 32 + rg * 16 + l16) * 72 + quad * 8]);
            ap[rg][1] = ldfrag(&lP[(wave * 32 + rg * 16 + l16) * 72 + 32 + quad * 8]);
        }
        bf16x8 vf[4][2];
        #pragma unroll
        for (int ni = 0; ni < 4; ++ni) {
            vf[ni][0] = ldfrag(&lV[(ni * 16 + l16) * 72 + quad * 8]);
            vf[ni][1] = ldfrag(&lV[(ni * 16 + l16) * 72 + 32 + quad * 8]);
        }
        #pragma unroll
        for (int rg = 0; rg < 2; ++rg)
            #pragma unroll
            for (int ni = 0; ni < 4; ++ni) {
                o[rg][ni] = mfma16(ap[rg][0], vf[ni][0], o[rg][ni]);
                o[rg][ni] = mfma16(ap[rg][1], vf[ni][1], o[rg][ni]);
            }
    }
    #pragma unroll
    for (int off = 1; off < 16; off <<= 1)
        #pragma unroll
        for (int rg = 0; rg < 2; ++rg)
            #pragma unroll
            for (int r = 0; r < 4; ++r)
                ps_acc[rg][r] += __shfl_xor(ps_acc[rg][r], off);
    float rl[2][4];
    #pragma unroll
    for (int rg = 0; rg < 2; ++rg)
        #pragma unroll
        for (int r = 0; r < 4; ++r) rl[rg][r] = 1.f / ps_acc[rg][r];
    #pragma unroll
    for (int rg = 0; rg < 2; ++rg)
        #pragma unroll
        for (int ni = 0; ni < 4; ++ni)
            #pragma unroll
            for (int r = 0; r < 4; ++r) {
                const int row = q0 + wave * 32 + rg * 16 + quad * 4 + r;
                attb[(size_t)(bb * 1024 + row) * 1024 + h * 64 + ni * 16 + l16] =
                    f2bf_hw(o[rg][ni][r] * rl[rg][r]);
            }
}

// ---------- residual (bf16 y) + LayerNorm ----------
__global__ __launch_bounds__(256) void ln_res(const u16* __restrict__ ybf,
                                              const u16* __restrict__ xpb,
                                              const float* __restrict__ a2,
                                              const float* __restrict__ b2,
                                              float* __restrict__ out) {
    const int row = blockIdx.x, tid = threadIdx.x;
    const size_t base = (size_t)row * 1024;
    const int j = tid * 4;
    const u16x4 yv = *(const u16x4*)&ybf[base + j];
    const u16x4 xv = *(const u16x4*)&xpb[base + j];
    float x[4] = {bf2f(yv.x) + bf2f(xv.x), bf2f(yv.y) + bf2f(xv.y),
                  bf2f(yv.z) + bf2f(xv.z), bf2f(yv.w) + bf2f(xv.w)};
    float s = 0.f, ss = 0.f;
    #pragma unroll
    for (int i = 0; i < 4; ++i) { s += x[i]; ss += x[i] * x[i]; }
    #pragma unroll
    for (int off = 1; off < 64; off <<= 1) {
        s += __shfl_xor(s, off);
        ss += __shfl_xor(ss, off);
    }
    __shared__ float rs[4], rss[4];
    const int wave = tid >> 6, lane = tid & 63;
    if (lane == 0) { rs[wave] = s; rss[wave] = ss; }
    __syncthreads();
    s = rs[0] + rs[1] + rs[2] + rs[3];
    ss = rss[0] + rss[1] + rss[2] + rss[3];
    const float mean = s * (1.f / 1024.f);
    float var = (ss - s * mean) * (1.f / 1023.f);
    var = fmaxf(var, 0.f);
    const float inv = 1.f / (sqrtf(var) + 1e-6f);
    const float4 av = *(const float4*)&a2[j];
    const float4 bv = *(const float4*)&b2[j];
    float4 ov;
    ov.x = av.x * (x[0] - mean) * inv + bv.x;
    ov.y = av.y * (x[1] - mean) * inv + bv.y;
    ov.z = av.z * (x[2] - mean) * inv + bv.z;
    ov.w = av.w * (x[3] - mean) * inv + bv.w;
    *(float4*)&out[base + j] = ov;
}

extern "C" void kernel_launch(void* const* d_in, const int* in_sizes, int n_in,
                              void* d_out, int out_size, void* d_ws, size_t ws_size,
                              hipStream_t stream) {
    (void)in_sizes; (void)n_in; (void)out_size;
    const float* y   = (const float*)d_in[0];
    const int*   msk = (const int*)d_in[1];
    const float* Wq  = (const float*)d_in[2];
    const float* bq  = (const float*)d_in[3];
    const float* Wk  = (const float*)d_in[4];
    const float* bkb = (const float*)d_in[5];
    const float* Wv  = (const float*)d_in[6];
    const float* bv  = (const float*)d_in[7];
    const float* Wm  = (const float*)d_in[8];
    const float* bm  = (const float*)d_in[9];
    const float* a2  = (const float*)d_in[10];
    const float* b2  = (const float*)d_in[11];
    float* out = (float*)d_out;

    char* ws = (char*)d_ws;
    const size_t MB = 1u << 20;
    if (ws_size < 72 * MB) return;  // need 72 MB of scratch
    u16* yb  = (u16*)(ws);             // 16 MB, stays LIVE (ln_res reads it)
    u16* wqb = (u16*)(ws + 16 * MB);   // wq/wk/wv/wm contiguous (8 MB)
    u16* wmb = (u16*)(ws + 22 * MB);
    u16* qb  = (u16*)(ws + 24 * MB);   // 16 MB (reused as bf16 xp after attn)
    u16* kb  = (u16*)(ws + 40 * MB);   // 16 MB
    u16* vb  = (u16*)(ws + 56 * MB);   // 16 MB (attn reads it live)
    u16* xpb  = qb;   // qb dead after attn

    int* idxb = (int*)d_out;                       // 8 x 1024 ints
    int* cntb = idxb + 8192;                       // 8 ints
    u16* attb = (u16*)((char*)d_out + 16 * MB);    // 16 MB

    conv_all<<<12289, 256, 0, stream>>>(y, Wq, Wk, Wv, Wm, yb, wqb,
                                        msk, idxb, cntb);

    // fused QKV via 8-phase 256^2 kernel: M=8192, N=3072 -> 32x12 = 384 blocks
    gemm8_bt<<<dim3(384), 512, 0, stream>>>(
        yb, wqb, bq, bkb, bv, qb, kb, vb, 1024, 12);

    attn<<<dim3(1024), 256, 0, stream>>>(qb, kb, vb, idxb, cntb, attb);

    // M-proj: N=1024, bf16 out (round-9 proven config, unsplit)
    gemm_bt<<<dim3(8, 64), 256, 0, stream>>>(
        attb, wmb, bm, bm, bm, xpb, xpb, xpb, 1024);

    ln_res<<<8192, 256, 0, stream>>>(yb, xpb, a2, b2, out);
}

// Round 2
// 272.442 us; speedup vs baseline: 1.0241x; 1.0241x over previous
//
#include <hip/hip_runtime.h>

#define DEVFN __device__ __forceinline__

typedef unsigned short u16;
typedef __attribute__((ext_vector_type(8))) unsigned short u16x8;
typedef __attribute__((ext_vector_type(4))) unsigned short u16x4;
typedef __attribute__((ext_vector_type(8))) __bf16 bf16x8;
typedef __attribute__((ext_vector_type(4))) float f32x4;

// ---------- helpers ----------
DEVFN u16 f2bf_hw(float f) {  // hardware RNE convert (single v_cvt)
    return __builtin_bit_cast(u16, (__bf16)f);
}

DEVFN float bf2f(u16 h) {
    unsigned u = (unsigned)h << 16;
    return __builtin_bit_cast(float, u);
}

DEVFN bf16x8 ldfrag(const u16* p) {
    return __builtin_bit_cast(bf16x8, *(const u16x8*)p);
}

DEVFN f32x4 mfma16(bf16x8 a, bf16x8 b, f32x4 c) {
    return __builtin_amdgcn_mfma_f32_16x16x32_bf16(a, b, c, 0, 0, 0);
}

// async global->LDS, 16B per lane; l must be the wave-uniform base
DEVFN void async16(const u16* g, u16* l) {
    __builtin_amdgcn_global_load_lds(
        (const __attribute__((address_space(1))) void*)g,
        (__attribute__((address_space(3))) void*)l, 16, 0, 0);
}

// ---------- fp32->bf16 converts + mask compaction, ONE dispatch ----------
__global__ __launch_bounds__(256) void conv_all(const float* __restrict__ y,
                                                const float* __restrict__ w0,
                                                const float* __restrict__ w1,
                                                const float* __restrict__ w2,
                                                const float* __restrict__ w3,
                                                u16* __restrict__ yb,
                                                u16* __restrict__ wb,
                                                const int* __restrict__ mask,
                                                int* __restrict__ idx,
                                                int* __restrict__ cnt) {
    const int b = blockIdx.x;
    if (b >= 12288) {
        const int wave = threadIdx.x >> 6, lane = threadIdx.x & 63;
        for (int bb = wave; bb < 8; bb += 4) {
            const int* m = mask + bb * 1024;
            int* ib = idx + bb * 1024;
            int base = 0;
            for (int t = 0; t < 16; ++t) {
                const int pos = t * 64 + lane;
                const int valid = (m[pos] == 0) ? 1 : 0;
                const unsigned long long bal = __ballot(valid);
                const int pre = __popcll(bal & ((1ull << lane) - 1ull));
                if (valid) ib[base + pre] = pos;
                base += (int)__popcll(bal);
            }
            if (lane == 0) cnt[bb] = base;
            for (int i = base + lane; i < 1024; i += 64) ib[i] = 0;  // safe pad
        }
        return;
    }
    const float* src;
    u16* dst;
    int i;
    if (b < 8192) {
        src = y; dst = yb;
        i = b * 1024 + threadIdx.x * 4;
    } else {
        const int g = (b - 8192) >> 10;
        src = g == 0 ? w0 : (g == 1 ? w1 : (g == 2 ? w2 : w3));
        dst = wb + (size_t)g * 1024 * 1024;
        i = ((b - 8192) & 1023) * 1024 + threadIdx.x * 4;
    }
    const float4 v = *(const float4*)&src[i];
    u16x4 o;
    o.x = f2bf_hw(v.x); o.y = f2bf_hw(v.y);
    o.z = f2bf_hw(v.z); o.w = f2bf_hw(v.w);
    *(u16x4*)&dst[i] = o;
}

// ---------- pipelined 256x128 GEMM (T1+T2+T3+T4+T5), bf16 out ----------
// C[M,N] = A[M,K] * Bt[N,K]^T + bias. 512 thr = 8 waves (4M x 2N), per-wave
// 64x64 output (4x4 frags), BK=64. Tile 256x128 chosen for EXACT grid
// quantization on both GEMMs: QKV 32x24 = 768 = 3/CU, M-proj 32x8 = 256 =
// 1/CU (round-1 post-mortem: 384-block grid capped QKV at 75% CU util).
// LDS 96 KiB: 2 buf x {A [256][64] @0 (16384 u16), B [128][64] @16384}.
//
// Per K-tile, 2 phases of 16 MFMA/wave (same granularity as m201 template):
//   p1: read A mi0-3 (8 ds) + B ni0-1 (4 ds) -> mfma m0-3 x n0-1
//   p2: read B ni2-3 (4 ds)                  -> mfma m0-3 x n2-3
// Stage ledger (global_load_lds, WAR-safe via the 2-barrier phase pattern):
//   t.p1: stage (t+1).B into buf^1  [old = (t-1).B, reads done by (t-1).p2
//         lgkmcnt(0), published by (t-1)'s final barrier]
//   t.p2: stage (t+2).A (2 chunks) into buf [t's A reads done by t.p1
//         lgkmcnt(0), published by p1's 2nd barrier]
// End-of-tile wait: vmcnt(4) = newest 4 ops ((t+2).A) may stay in flight;
// (t+1).A [issued (t-1).p2] and (t+1).B [issued t.p1] guaranteed done ->
// barrier publishes across waves. Tail t>=NT-2 drains vmcnt(0).
// Swizzle (both-sides, 0-conflict verified round 1): linear LDS dest,
// source fetches slot sc^sr of its row, reads XOR slot with row&7.
// K ascending in 32-chunks -> accumulation order identical to prior rounds.
__global__ __launch_bounds__(512, 2) void gemm8b(const u16* __restrict__ A,
                                                 const u16* __restrict__ Bt,
                                                 const float* __restrict__ b0,
                                                 const float* __restrict__ b1,
                                                 const float* __restrict__ b2,
                                                 u16* __restrict__ C0,
                                                 u16* __restrict__ C1,
                                                 u16* __restrict__ C2,
                                                 int K, int NBX) {
    __shared__ u16 lds[2][24576];  // per buf: A @0 (16384), B @16384 (8192)
    const int NT = K >> 6;
    const int tid = threadIdx.x;
    const int wave = tid >> 6, lane = tid & 63;
    const int quad = lane >> 4, l16 = lane & 15;
    const int wm = wave >> 1, wn = wave & 1;
    // XCD-bijective chunked swizzle (grids: 768, 256 -> both % 8 == 0)
    const int nwg = gridDim.x, cpx = nwg >> 3;
    const int sb = (blockIdx.x & 7) * cpx + (blockIdx.x >> 3);
    const int bx = sb % NBX, by = sb / NBX;
    const int m0 = by * 256, n0 = bx * 128;
    // staging: per-thread pre-swizzled source, linear LDS dest
    const int sr = lane >> 3, sc = lane & 7;
    const int scs = (sc ^ sr) << 3;
    const u16* Ag = A + (size_t)(m0 + wave * 8 + sr) * K + scs;
    const u16* Bg = Bt + (size_t)(n0 + wave * 8 + sr) * K + scs;
    const size_t rstep = (size_t)64 * K;  // 64-row step
    // read-side swizzled offsets (u16 units); ks=1 frag = rof ^ 32
    const int swz = (quad ^ (l16 & 7)) << 3;
    const int rofA = (wm * 64 + l16) * 64 + swz;
    const int rofB = (wn * 64 + l16) * 64 + swz;

#define STAGE(gp, lp)                                        \
    do {                                                     \
        async16((gp), (lp) + wave * 512);                    \
        async16((gp) + rstep, (lp) + 4096 + wave * 512);     \
    } while (0)

    f32x4 acc[4][4] = {};

    // prologue: t0.A0, t0.A1, t0.B (6 ops), then t1.A0, t1.A1 (4 ops)
    STAGE(Ag, &lds[0][0]);
    STAGE(Ag + 2 * rstep, &lds[0][8192]);
    STAGE(Bg, &lds[0][16384]);
    STAGE(Ag + 64, &lds[1][0]);
    STAGE(Ag + 2 * rstep + 64, &lds[1][8192]);
    asm volatile("s_waitcnt vmcnt(4)" ::: "memory");  // t0 complete
    __builtin_amdgcn_s_barrier();

    for (int t = 0; t < NT; ++t) {
        const int buf = t & 1;
        const u16* Ar = &lds[buf][0];
        const u16* Br = &lds[buf][16384];
        bf16x8 af[4][2], bfr[4][2];
        // ---- phase 1: A mi0-3 + B ni0-1 ----
        #pragma unroll
        for (int mi = 0; mi < 4; ++mi) {
            af[mi][0] = ldfrag(Ar + mi * 1024 + rofA);
            af[mi][1] = ldfrag(Ar + mi * 1024 + (rofA ^ 32));
        }
        #pragma unroll
        for (int ni = 0; ni < 2; ++ni) {
            bfr[ni][0] = ldfrag(Br + ni * 1024 + rofB);
            bfr[ni][1] = ldfrag(Br + ni * 1024 + (rofB ^ 32));
        }
        if (t + 1 < NT) STAGE(Bg + (t + 1) * 64, &lds[buf ^ 1][16384]);
        __builtin_amdgcn_s_barrier();
        asm volatile("s_waitcnt lgkmcnt(0)" ::: "memory");
        __builtin_amdgcn_s_setprio(1);
        #pragma unroll
        for (int mi = 0; mi < 4; ++mi)
            #pragma unroll
            for (int ni = 0; ni < 2; ++ni) {
                acc[mi][ni] = mfma16(af[mi][0], bfr[ni][0], acc[mi][ni]);
                acc[mi][ni] = mfma16(af[mi][1], bfr[ni][1], acc[mi][ni]);
            }
        __builtin_amdgcn_s_setprio(0);
        __builtin_amdgcn_s_barrier();
        // ---- phase 2: B ni2-3 ----
        #pragma unroll
        for (int ni = 2; ni < 4; ++ni) {
            bfr[ni][0] = ldfrag(Br + ni * 1024 + rofB);
            bfr[ni][1] = ldfrag(Br + ni * 1024 + (rofB ^ 32));
        }
        if (t + 2 < NT) {
            STAGE(Ag + (t + 2) * 64, &lds[buf][0]);
            STAGE(Ag + 2 * rstep + (t + 2) * 64, &lds[buf][8192]);
        }
        __builtin_amdgcn_s_barrier();
        asm volatile("s_waitcnt lgkmcnt(0)" ::: "memory");
        __builtin_amdgcn_s_setprio(1);
        #pragma unroll
        for (int mi = 0; mi < 4; ++mi)
            #pragma unroll
            for (int ni = 2; ni < 4; ++ni) {
                acc[mi][ni] = mfma16(af[mi][0], bfr[ni][0], acc[mi][ni]);
                acc[mi][ni] = mfma16(af[mi][1], bfr[ni][1], acc[mi][ni]);
            }
        __builtin_amdgcn_s_setprio(0);
        if (t < NT - 2)
            asm volatile("s_waitcnt vmcnt(4)" ::: "memory");
        else
            asm volatile("s_waitcnt vmcnt(0)" ::: "memory");
        __builtin_amdgcn_s_barrier();
    }
#undef STAGE
    // epilogue: bias + bf16 store, col>>10 selects output buffer
    const int wrow = m0 + wm * 64 + quad * 4;
    #pragma unroll
    for (int ni = 0; ni < 4; ++ni) {
        const int col = n0 + wn * 64 + ni * 16 + l16;
        const int cs = col >> 10;
        const int c = col & 1023;
        const float* bp = cs == 0 ? b0 : (cs == 1 ? b1 : b2);
        u16* cp = cs == 0 ? C0 : (cs == 1 ? C1 : C2);
        const float bb = bp[c];
        #pragma unroll
        for (int mi = 0; mi < 4; ++mi)
            #pragma unroll
            for (int r = 0; r < 4; ++r) {
                const int row = wrow + mi * 16 + r;
                cp[(size_t)row * 1024 + c] = f2bf_hw(acc[mi][ni][r] + bb);
            }
    }
}

// ---------- flash attention over COMPACTED K/V, in-kernel V transpose ----------
__global__ __launch_bounds__(256) void attn(const u16* __restrict__ qb,
                                            const u16* __restrict__ kb,
                                            const u16* __restrict__ vb,
                                            const int* __restrict__ idxb,
                                            const int* __restrict__ cntb,
                                            u16* __restrict__ attb) {
    const int lin = blockIdx.x;
    const int xcd = lin & 7, slot = lin >> 3;          // slot 0..127
    const int bh = xcd * 16 + (slot >> 3);
    const int q0 = (slot & 7) * 128;
    const int bb = bh >> 4, h = bh & 15;
    const int tid = threadIdx.x, wave = tid >> 6, lane = tid & 63;
    const int quad = lane >> 4, l16 = lane & 15;
    __shared__ u16 lK[64 * 72];
    __shared__ u16 lV[64 * 72];
    __shared__ u16 lP[128 * 72];

    const int cn = cntb[bb];
    const int kEnd = (cn + 63) & ~63;
    const int* ib = idxb + bb * 1024;

    bf16x8 aq[2][2];
    #pragma unroll
    for (int rg = 0; rg < 2; ++rg) {
        const int qrow = q0 + wave * 32 + rg * 16 + l16;
        const u16* qp = qb + (size_t)(bb * 1024 + qrow) * 1024 + h * 64 + quad * 8;
        aq[rg][0] = ldfrag(qp);
        aq[rg][1] = ldfrag(qp + 32);
    }

    f32x4 o[2][4] = {};
    float ps_acc[2][4] = {};

    const int srow = tid >> 3, scol = (tid & 7) * 8;
    const u16* kbase = kb + (size_t)(bb * 1024) * 1024 + h * 64 + scol;
    const u16* vbase = vb + (size_t)(bb * 1024) * 1024 + h * 64 + scol;

    int gi0 = ib[srow], gi1 = ib[srow + 32];
    u16x8 nk0 = *(const u16x8*)(kbase + (size_t)gi0 * 1024);
    u16x8 nk1 = *(const u16x8*)(kbase + (size_t)gi1 * 1024);
    u16x8 nv0 = *(const u16x8*)(vbase + (size_t)gi0 * 1024);
    u16x8 nv1 = *(const u16x8*)(vbase + (size_t)gi1 * 1024);

    const float C = 0.18033688011112043f;  // 0.125 * log2(e)

    for (int kt = 0; kt < kEnd; kt += 64) {
        __syncthreads();
        *(u16x8*)&lK[srow * 72 + scol] = nk0;
        *(u16x8*)&lK[(srow + 32) * 72 + scol] = nk1;
        #pragma unroll
        for (int j = 0; j < 8; ++j) {
            lV[(scol + j) * 72 + srow] = nv0[j];
            lV[(scol + j) * 72 + srow + 32] = nv1[j];
        }
        __syncthreads();
        const int ktn = kt + 64;
        if (ktn < kEnd) {
            gi0 = ib[ktn + srow]; gi1 = ib[ktn + srow + 32];
            nk0 = *(const u16x8*)(kbase + (size_t)gi0 * 1024);
            nk1 = *(const u16x8*)(kbase + (size_t)gi1 * 1024);
            nv0 = *(const u16x8*)(vbase + (size_t)gi0 * 1024);
            nv1 = *(const u16x8*)(vbase + (size_t)gi1 * 1024);
        }

        bf16x8 kf[4][2];
        #pragma unroll
        for (int n = 0; n < 4; ++n) {
            kf[n][0] = ldfrag(&lK[(n * 16 + l16) * 72 + quad * 8]);
            kf[n][1] = ldfrag(&lK[(n * 16 + l16) * 72 + 32 + quad * 8]);
        }
        f32x4 s[2][4];
        #pragma unroll
        for (int rg = 0; rg < 2; ++rg)
            #pragma unroll
            for (int n = 0; n < 4; ++n) {
                f32x4 t = {};
                t = mfma16(aq[rg][0], kf[n][0], t);
                t = mfma16(aq[rg][1], kf[n][1], t);
                s[rg][n] = t;
            }
        float bias[4];
        #pragma unroll
        for (int n = 0; n < 4; ++n)
            bias[n] = (kt + n * 16 + l16 < cn) ? 0.0f : -1e9f;
        #pragma unroll
        for (int rg = 0; rg < 2; ++rg)
            #pragma unroll
            for (int n = 0; n < 4; ++n)
                #pragma unroll
                for (int r = 0; r < 4; ++r) {
                    const float p =
                        __builtin_amdgcn_exp2f(__builtin_fmaf(s[rg][n][r], C, bias[n]));
                    ps_acc[rg][r] += p;
                    lP[(wave * 32 + rg * 16 + quad * 4 + r) * 72 + n * 16 + l16] =
                        f2bf_hw(p);
                }
        __asm__ __volatile__("s_waitcnt lgkmcnt(0)" ::: "memory");
        bf16x8 ap[2][2];
        #pragma unroll
        for (int rg = 0; rg < 2; ++rg) {
            ap[rg][0] = ldfrag(&lP[(wave * 32 + rg * 16 + l16) * 72 + quad * 8]);
            ap[rg][1] = ldfrag(&lP[(wave * 32 + rg * 16 + l16) * 72 + 32 + quad * 8]);
        }
        bf16x8 vf[4][2];
        #pragma unroll
        for (int ni = 0; ni < 4; ++ni) {
            vf[ni][0] = ldfrag(&lV[(ni * 16 + l16) * 72 + quad * 8]);
            vf[ni][1] = ldfrag(&lV[(ni * 16 + l16) * 72 + 32 + quad * 8]);
        }
        #pragma unroll
        for (int rg = 0; rg < 2; ++rg)
            #pragma unroll
            for (int ni = 0; ni < 4; ++ni) {
                o[rg][ni] = mfma16(ap[rg][0], vf[ni][0], o[rg][ni]);
                o[rg][ni] = mfma16(ap[rg][1], vf[ni][1], o[rg][ni]);
            }
    }
    #pragma unroll
    for (int off = 1; off < 16; off <<= 1)
        #pragma unroll
        for (int rg = 0; rg < 2; ++rg)
            #pragma unroll
            for (int r = 0; r < 4; ++r)
                ps_acc[rg][r] += __shfl_xor(ps_acc[rg][r], off);
    float rl[2][4];
    #pragma unroll
    for (int rg = 0; rg < 2; ++rg)
        #pragma unroll
        for (int r = 0; r < 4; ++r) rl[rg][r] = 1.f / ps_acc[rg][r];
    #pragma unroll
    for (int rg = 0; rg < 2; ++rg)
        #pragma unroll
        for (int ni = 0; ni < 4; ++ni)
            #pragma unroll
            for (int r = 0; r < 4; ++r) {
                const int row = q0 + wave * 32 + rg * 16 + quad * 4 + r;
                attb[(size_t)(bb * 1024 + row) * 1024 + h * 64 + ni * 16 + l16] =
                    f2bf_hw(o[rg][ni][r] * rl[rg][r]);
            }
}

// ---------- residual (bf16 y) + LayerNorm ----------
__global__ __launch_bounds__(256) void ln_res(const u16* __restrict__ ybf,
                                              const u16* __restrict__ xpb,
                                              const float* __restrict__ a2,
                                              const float* __restrict__ b2,
                                              float* __restrict__ out) {
    const int row = blockIdx.x, tid = threadIdx.x;
    const size_t base = (size_t)row * 1024;
    const int j = tid * 4;
    const u16x4 yv = *(const u16x4*)&ybf[base + j];
    const u16x4 xv = *(const u16x4*)&xpb[base + j];
    float x[4] = {bf2f(yv.x) + bf2f(xv.x), bf2f(yv.y) + bf2f(xv.y),
                  bf2f(yv.z) + bf2f(xv.z), bf2f(yv.w) + bf2f(xv.w)};
    float s = 0.f, ss = 0.f;
    #pragma unroll
    for (int i = 0; i < 4; ++i) { s += x[i]; ss += x[i] * x[i]; }
    #pragma unroll
    for (int off = 1; off < 64; off <<= 1) {
        s += __shfl_xor(s, off);
        ss += __shfl_xor(ss, off);
    }
    __shared__ float rs[4], rss[4];
    const int wave = tid >> 6, lane = tid & 63;
    if (lane == 0) { rs[wave] = s; rss[wave] = ss; }
    __syncthreads();
    s = rs[0] + rs[1] + rs[2] + rs[3];
    ss = rss[0] + rss[1] + rss[2] + rss[3];
    const float mean = s * (1.f / 1024.f);
    float var = (ss - s * mean) * (1.f / 1023.f);
    var = fmaxf(var, 0.f);
    const float inv = 1.f / (sqrtf(var) + 1e-6f);
    const float4 av = *(const float4*)&a2[j];
    const float4 bv = *(const float4*)&b2[j];
    float4 ov;
    ov.x = av.x * (x[0] - mean) * inv + bv.x;
    ov.y = av.y * (x[1] - mean) * inv + bv.y;
    ov.z = av.z * (x[2] - mean) * inv + bv.z;
    ov.w = av.w * (x[3] - mean) * inv + bv.w;
    *(float4*)&out[base + j] = ov;
}

extern "C" void kernel_launch(void* const* d_in, const int* in_sizes, int n_in,
                              void* d_out, int out_size, void* d_ws, size_t ws_size,
                              hipStream_t stream) {
    (void)in_sizes; (void)n_in; (void)out_size;
    const float* y   = (const float*)d_in[0];
    const int*   msk = (const int*)d_in[1];
    const float* Wq  = (const float*)d_in[2];
    const float* bq  = (const float*)d_in[3];
    const float* Wk  = (const float*)d_in[4];
    const float* bkb = (const float*)d_in[5];
    const float* Wv  = (const float*)d_in[6];
    const float* bv  = (const float*)d_in[7];
    const float* Wm  = (const float*)d_in[8];
    const float* bm  = (const float*)d_in[9];
    const float* a2  = (const float*)d_in[10];
    const float* b2  = (const float*)d_in[11];
    float* out = (float*)d_out;

    char* ws = (char*)d_ws;
    const size_t MB = 1u << 20;
    if (ws_size < 72 * MB) return;  // need 72 MB of scratch
    u16* yb  = (u16*)(ws);             // 16 MB, stays LIVE (ln_res reads it)
    u16* wqb = (u16*)(ws + 16 * MB);   // wq/wk/wv/wm contiguous (8 MB)
    u16* wmb = (u16*)(ws + 22 * MB);
    u16* qb  = (u16*)(ws + 24 * MB);   // 16 MB (reused as bf16 xp after attn)
    u16* kb  = (u16*)(ws + 40 * MB);   // 16 MB
    u16* vb  = (u16*)(ws + 56 * MB);   // 16 MB (attn reads it live)
    u16* xpb  = qb;   // qb dead after attn

    int* idxb = (int*)d_out;                       // 8 x 1024 ints
    int* cntb = idxb + 8192;                       // 8 ints
    u16* attb = (u16*)((char*)d_out + 16 * MB);    // 16 MB

    conv_all<<<12289, 256, 0, stream>>>(y, Wq, Wk, Wv, Wm, yb, wqb,
                                        msk, idxb, cntb);

    // fused QKV: M=8192, N=3072, tile 256x128 -> 32x24 = 768 blocks = 3/CU
    gemm8b<<<dim3(768), 512, 0, stream>>>(
        yb, wqb, bq, bkb, bv, qb, kb, vb, 1024, 24);

    attn<<<dim3(1024), 256, 0, stream>>>(qb, kb, vb, idxb, cntb, attb);

    // M-proj: M=8192, N=1024, tile 256x128 -> 32x8 = 256 blocks = 1/CU
    gemm8b<<<dim3(256), 512, 0, stream>>>(
        attb, wmb, bm, bm, bm, xpb, xpb, xpb, 1024, 8);

    ln_res<<<8192, 256, 0, stream>>>(yb, xpb, a2, b2, out);
}